// Round 9
// baseline (145.135 us; speedup 1.0000x reference)
//
#include <hip/hip_runtime.h>
#include <hip/hip_fp16.h>

typedef unsigned long long u64;
typedef unsigned int u32;
typedef float float4a __attribute__((ext_vector_type(4), aligned(4)));

// Problem constants (setup_inputs: B=8, Hs=Ws=256, H=W=512, niter=5)
#define B_    8
#define HS_   256
#define WS_   256
#define H_    512
#define W_    512
#define HW_   (H_ * W_)
#define TO_Y  16                 // output rows per block / bucket band height
#define NB    32                 // bands per batch
#define WR    36                 // window rows = TO_Y + 2*10 (dilate5+erode5 halo)
#define COFF  6                  // column pad offset (padded cols -6..517)
#define KC    524                // key-plane columns (stride, u32)
#define VSTR  528                // value-plane stride (u32)
#define INFW  0xFFFFFFFFu
#define CAPB  16384              // bucket capacity (expected ~8K, huge margin)

// ---------------------------------------------------------------------------
// Bilinear upsample of (src - base), bit-exact vs the numpy reference
// (contraction off; same op order). Pixel PAIRS load as float4 (16 B).
// x0==255 (only output col 511, wx==0): shift pair to (254,255), weights
// (0,1) — identical result.
// ---------------------------------------------------------------------------
__device__ __forceinline__ void bilin_disp(const float* __restrict__ src,
                                           const float* __restrict__ base,
                                           int b, int y, int x,
                                           float& dx, float& dy) {
#pragma clang fp contract(off)
    float cy = ((float)y + 0.5f) * 0.5f - 0.5f;
    cy = fminf(fmaxf(cy, 0.0f), 255.0f);
    int   y0 = (int)floorf(cy);
    int   y1 = min(y0 + 1, HS_ - 1);
    float wy = cy - (float)y0;

    float cx = ((float)x + 0.5f) * 0.5f - 0.5f;
    cx = fminf(fmaxf(cx, 0.0f), 255.0f);
    int   x0 = (int)floorf(cx);
    float wx = cx - (float)x0;

    float omy = 1.0f - wy;
    float wA, wB;
    int xs;
    if (x0 >= WS_ - 1) { xs = WS_ - 2; wA = 0.0f; wB = 1.0f; }
    else               { xs = x0;      wA = 1.0f - wx; wB = wx; }

    const float4a* S0 = (const float4a*)(src  + ((b * HS_ + y0) * WS_ + xs) * 2);
    const float4a* S1 = (const float4a*)(src  + ((b * HS_ + y1) * WS_ + xs) * 2);
    const float4a* B0 = (const float4a*)(base + (y0 * WS_ + xs) * 2);
    const float4a* B1 = (const float4a*)(base + (y1 * WS_ + xs) * 2);
    float4a s0 = *S0, s1 = *S1, b0 = *B0, b1 = *B1;

    float a00x = s0.x - b0.x, a00y = s0.y - b0.y;
    float a01x = s0.z - b0.z, a01y = s0.w - b0.w;
    float a10x = s1.x - b1.x, a10y = s1.y - b1.y;
    float a11x = s1.z - b1.z, a11y = s1.w - b1.w;

    float r0x = a00x * omy + a10x * wy;   // blend along y first (matches ref)
    float r0y = a00y * omy + a10y * wy;
    float r1x = a01x * omy + a11x * wy;
    float r1y = a01y * omy + a11y * wy;
    dx = (r0x * wA + r1x * wB) * 256.0f;  // * (W/2), exact pow2
    dy = (r0y * wA + r1y * wB) * 256.0f;
}

__device__ __forceinline__ u32 pack16(float x, float y) {
    __half hx = __float2half_rn(x), hy = __float2half_rn(y);
    return ((u32)__half_as_ushort(hy) << 16) | (u32)__half_as_ushort(hx);
}
__device__ __forceinline__ float2 unpack16(u32 p) {
    float2 f;
    f.x = __half2float(__ushort_as_half((unsigned short)(p & 0xFFFFu)));
    f.y = __half2float(__ushort_as_half((unsigned short)(p >> 16)));
    return f;
}

__device__ __forceinline__ u64 shfl_left(u64 v) {
    unsigned lo = __shfl_up((unsigned)v, 1);
    unsigned hi = __shfl_up((unsigned)(v >> 32), 1);
    u64 r = ((u64)hi << 32) | lo;
    return (threadIdx.x & 63) ? r : 0ull;
}
__device__ __forceinline__ u64 shfl_right(u64 v) {
    unsigned lo = __shfl_down((unsigned)v, 1);
    unsigned hi = __shfl_down((unsigned)(v >> 32), 1);
    u64 r = ((u64)hi << 32) | lo;
    return ((threadIdx.x & 63) == 63) ? 0ull : r;
}

// ---------------------------------------------------------------------------
// Pass 1: evaluate every source ONCE (bit-exact decisions), store payload
// pay[b][j] = half2(-dx,-dy), and append a u32 entry
//   (yi&15)<<27 | xi<<18 | j      (j = per-batch source index, 18 bits)
// into bucket[(b,band=yi>>4)] via LDS histogram + one global atomicAdd per
// active band per block + per-band-contiguous (coalesced) writes.
// Block remap: bid&7 = batch -> batch-b blocks pinned to XCD b (round-robin
// heuristic) so pay/bucket slices stay XCD-local for fused3_k.
// ---------------------------------------------------------------------------
__global__ void pre_k(const float* __restrict__ src,
                      const float* __restrict__ base,
                      u32* __restrict__ pay,
                      u32* __restrict__ gcount,
                      u32* __restrict__ bucket) {
    __shared__ u32 cnt[NB];
    __shared__ u32 bbase[NB];

    int bid = blockIdx.x;
    int b   = bid & 7;
    int t   = bid >> 3;                    // 0..1023
    int j   = t * 256 + threadIdx.x;       // per-batch source index
    int y   = j >> 9;
    int x   = j & (W_ - 1);

    if (threadIdx.x < NB) cnt[threadIdx.x] = 0;
    __syncthreads();

    float dx, dy;
    bilin_disp(src, base, b, y, x, dx, dy);
    pay[b * HW_ + j] = pack16(-dx, -dy);

    int xi = (int)rintf((float)x + dx);    // round-half-even == jnp.round
    int yi = (int)rintf((float)y + dy);
    bool inb = (xi >= 0 && xi < W_ && yi >= 0 && yi < H_);
    int band = 0, rank = 0;
    if (inb) {
        band = yi >> 4;
        rank = atomicAdd(&cnt[band], 1u);
    }
    __syncthreads();
    if (threadIdx.x < NB && cnt[threadIdx.x] > 0)
        bbase[threadIdx.x] = atomicAdd(&gcount[b * NB + threadIdx.x],
                                       cnt[threadIdx.x]);
    __syncthreads();
    if (inb) {
        u32 slotn = bbase[band] + rank;
        if (slotn < CAPB) {
            u32 e = ((u32)(yi & 15) << 27) | ((u32)xi << 18) | (u32)j;
            bucket[(b * NB + band) * CAPB + slotn] = e;
        }
    }
}

// ---------------------------------------------------------------------------
// Pass 2: fused bucket-scatter + payload gather + 5x diffusion + 5x erosion
// + compose. 256 blocks, id&7 = batch (XCD pin). Block (b,tile) needs window
// rows [Y0-10, Y0+26) -> buckets tile-1, tile, tile+1 EXACTLY (no SLK
// heuristic any more). Scatter = u32 LDS atomicMin of j-keys; winner payload
// fetched once per masked cell from pay[] into a separate stride-528 value
// plane (no repack, mask-build reads stride-1 conflict-free).
//
// Stencil correctness identical to R7/R8 (ring analysis): mask exact at
// ring>=5 after 5 dilations, >=10 after 5 erosions = output region (bits
// 10..25, lanes 16..47); value updates restricted to bits 6..29 x lanes
// 6..57; zero-value contamination capped at ring 9 < 10; validm pins
// out-of-padded-array cells unmasked (True-pad erosion rule never fires).
// val plane explicitly 0-initialized: branchless conv multiplies wq=0 by
// whatever is there (R6 NaN lesson).
// ---------------------------------------------------------------------------
__launch_bounds__(1024)
__global__ void fused3_k(const u32* __restrict__ pay,
                         const u32* __restrict__ gcount,
                         const u32* __restrict__ bucket,
                         const float* __restrict__ kern,
                         const float* __restrict__ tgt,
                         float* __restrict__ out) {
    __shared__ u32 key[WR * KC];           // 75456 B
    __shared__ u32 val[WR * VSTR];         // 76032 B

    int id   = blockIdx.x;                 // 0..255
    int b    = id & 7;                     // batch == XCD (round-robin pin)
    int tile = id >> 3;                    // 0..31
    int Y0   = tile * TO_Y;
    int w0   = Y0 - 10;                    // window row 0 (output coords)
    int tid  = threadIdx.x;

    float kw[9];
#pragma unroll
    for (int q = 0; q < 9; q++) kw[q] = kern[q];

    // ---- phase 0: init key=INFW, val=0 ----
    for (int i = tid; i < WR * KC; i += 1024) key[i] = INFW;
    for (int i = tid; i < WR * VSTR; i += 1024) val[i] = 0u;
    __syncthreads();

    // ---- phase 1: scatter from 3 buckets (exact; ~24K entries) ----
    for (int q = tile - 1; q <= tile + 1; q++) {
        if (q < 0 || q >= NB) continue;
        u32 cntq = min(gcount[b * NB + q], (u32)CAPB);
        const u32* bk = bucket + (b * NB + q) * CAPB;
        int ybase = q * TO_Y - w0;         // band row 0 in window coords
        for (u32 i = tid; i < cntq; i += 1024) {
            u32 e  = bk[i];
            int wr = ybase + (int)((e >> 27) & 15u);
            if ((unsigned)wr < WR) {
                int xc = (int)((e >> 18) & 511u);
                atomicMin(&key[wr * KC + xc + COFF], e & 0x3FFFFu);
            }
        }
    }
    __syncthreads();

    // ---- phase 2: payload gather (each masked cell once, cooperative) ----
    {
        const u32* pb = pay + b * HW_;
        for (int idx = tid; idx < WR * KC; idx += 1024) {
            u32 k = key[idx];
            if (k != INFW) {
                int rr = idx / KC;
                int cc = idx - rr * KC;
                val[rr * VSTR + cc] = pb[k];
            }
        }
    }
    __syncthreads();

    // ---- phase 3: per-lane column mask (stride-1, conflict-free) ----
    int wv   = tid >> 6;
    int lane = tid & 63;
    int col  = 32 * wv - 16 + lane;        // output-coord column of this lane
    int cls  = col + COFF;                 // key/val column index
    bool colin = (col >= -COFF) && (col <= W_ + 5);   // padded cols [-6,517]

    u64 m = 0;
    if (colin) {
#pragma unroll 6
        for (int r = 0; r < WR; r++)
            m |= (u64)(key[r * KC + cls] != INFW) << r;
    }

    int rlo = max(0, -COFF - w0);
    int rhi = min(WR - 1, (W_ + 5) - w0);
    u64 validm = colin ? ((((u64)1 << (rhi - rlo + 1)) - 1) << rlo) : 0ull;

    const u64 VROWS = (((u64)1 << 24) - 1) << 6;   // bits 6..29
    bool vlane = (lane >= 6 && lane <= 57);

    // ---- phase 4: 5 diffusion iterations ----
    for (int it = 0; it < 5; it++) {
        u64 mL = shfl_left(m), mR = shfl_right(m);
        u64 cand = ~m & ((m << 1) | (m >> 1) | mL | mR) & validm;
        u64 cv = vlane ? (cand & VROWS) : 0ull;
        while (cv) {
            int r = __builtin_ctzll(cv);
            cv &= cv - 1;
            float s = 0.0f, ax = 0.0f, ay = 0.0f;
#pragma unroll
            for (int dr = -1; dr <= 1; dr++) {
#pragma unroll
                for (int dc = -1; dc <= 1; dc++) {
                    if (dr == 0 && dc == 0) continue;
                    u64 nm = (dc < 0) ? mL : ((dc > 0) ? mR : m);
                    float wq = ((nm >> (r + dr)) & 1)
                                 ? kw[(dr + 1) * 3 + (dc + 1)] : 0.0f;
                    int cc = min(max(cls + dc, 0), KC - 1);  // clamp: wq==0 there
                    float2 nv = unpack16(val[(r + dr) * VSTR + cc]);
                    s += wq; ax += wq * nv.x; ay += wq * nv.y;
                }
            }
            val[r * VSTR + cls] = pack16(ax / s, ay / s);
        }
        m |= cand;
        __syncthreads();
    }

    // ---- phase 5: 5 erosion iterations (registers only) + compose ----
    for (int it = 0; it < 5; it++) {
        u64 mL = shfl_left(m), mR = shfl_right(m);
        m &= (m << 1) & (m >> 1) & mL & mR;
    }

    if (lane >= 16 && lane < 48) {
#pragma unroll 4
        for (int r = 10; r < 10 + TO_Y; r++) {
            int row = w0 + r;              // Y0 .. Y0+15, always in [0,512)
            bool on = (m >> r) & 1;
            float vx, vy;
            if (on) {
                float2 t = unpack16(val[r * VSTR + cls]);
                vx = t.x * (1.0f / 256.0f);   // 2/W exact
                vy = t.y * (1.0f / 256.0f);   // 2/H exact
            } else {
                vx = 4.0f; vy = 4.0f;
            }
            int ti = (row * W_ + col) * 2;
            float2 tg = *(const float2*)(tgt + ti);
            float2 ov; ov.x = tg.x + vx; ov.y = tg.y + vy;
            ((float2*)out)[(size_t)b * HW_ + row * W_ + col] = ov;
        }
    }
}

extern "C" void kernel_launch(void* const* d_in, const int* in_sizes, int n_in,
                              void* d_out, int out_size, void* d_ws, size_t ws_size,
                              hipStream_t stream) {
    const float* src  = (const float*)d_in[0];  // (8,256,256,2)
    const float* kern = (const float*)d_in[1];  // (3,3)
    const float* base = (const float*)d_in[2];  // (1,256,256,2)
    const float* tgt  = (const float*)d_in[3];  // (1,512,512,2)
    float* out = (float*)d_out;                 // (8,512,512,2)

    char* ws = (char*)d_ws;
    u32* gcount = (u32*)ws;                                   // 1 KB
    u32* pay    = (u32*)(ws + 1024);                          // 8 MB
    u32* bucket = (u32*)(ws + 1024 + (size_t)B_ * HW_ * 4);   // 16.8 MB

    hipMemsetAsync(gcount, 0, B_ * NB * sizeof(u32), stream);

    pre_k<<<(B_ * HW_) / 256, 256, 0, stream>>>(src, base, pay, gcount, bucket);
    fused3_k<<<256, 1024, 0, stream>>>(pay, gcount, bucket, kern, tgt, out);
}

// Round 10
// 139.740 us; speedup vs baseline: 1.0386x; 1.0386x over previous
//
#include <hip/hip_runtime.h>
#include <hip/hip_fp16.h>

typedef unsigned long long u64;
typedef unsigned int u32;
typedef float float4a __attribute__((ext_vector_type(4), aligned(4)));

// Problem constants (setup_inputs: B=8, Hs=Ws=256, H=W=512, niter=5)
#define B_    8
#define HS_   256
#define WS_   256
#define H_    512
#define W_    512
#define HW_   (H_ * W_)
#define TO_Y  8                  // output rows per block
#define NTY   64                 // row tiles per batch
#define BND   16                 // bucket band height
#define NB    32                 // bands per batch
#define WR    28                 // window rows = TO_Y + 2*10
#define COFF  6                  // column pad offset (padded cols -6..517)
#define PC    524                // real cells per window row
#define VSTR  531                // LDS plane stride (odd -> rows rotate banks)
#define INFW  0xFFFFFFFFu
#define CAPB  16384              // bucket capacity (expected ~8K, 2x margin)

// ---------------------------------------------------------------------------
// Bilinear upsample of (src - base), bit-exact vs the numpy reference
// (contraction off; same op order). Pixel PAIRS load as float4 (16 B).
// x0==255 (only output col 511, wx==0): shift pair to (254,255), weights
// (0,1) — identical result.
// ---------------------------------------------------------------------------
__device__ __forceinline__ void bilin_disp(const float* __restrict__ src,
                                           const float* __restrict__ base,
                                           int b, int y, int x,
                                           float& dx, float& dy) {
#pragma clang fp contract(off)
    float cy = ((float)y + 0.5f) * 0.5f - 0.5f;
    cy = fminf(fmaxf(cy, 0.0f), 255.0f);
    int   y0 = (int)floorf(cy);
    int   y1 = min(y0 + 1, HS_ - 1);
    float wy = cy - (float)y0;

    float cx = ((float)x + 0.5f) * 0.5f - 0.5f;
    cx = fminf(fmaxf(cx, 0.0f), 255.0f);
    int   x0 = (int)floorf(cx);
    float wx = cx - (float)x0;

    float omy = 1.0f - wy;
    float wA, wB;
    int xs;
    if (x0 >= WS_ - 1) { xs = WS_ - 2; wA = 0.0f; wB = 1.0f; }
    else               { xs = x0;      wA = 1.0f - wx; wB = wx; }

    const float4a* S0 = (const float4a*)(src  + ((b * HS_ + y0) * WS_ + xs) * 2);
    const float4a* S1 = (const float4a*)(src  + ((b * HS_ + y1) * WS_ + xs) * 2);
    const float4a* B0 = (const float4a*)(base + (y0 * WS_ + xs) * 2);
    const float4a* B1 = (const float4a*)(base + (y1 * WS_ + xs) * 2);
    float4a s0 = *S0, s1 = *S1, b0 = *B0, b1 = *B1;

    float a00x = s0.x - b0.x, a00y = s0.y - b0.y;
    float a01x = s0.z - b0.z, a01y = s0.w - b0.w;
    float a10x = s1.x - b1.x, a10y = s1.y - b1.y;
    float a11x = s1.z - b1.z, a11y = s1.w - b1.w;

    float r0x = a00x * omy + a10x * wy;   // blend along y first (matches ref)
    float r0y = a00y * omy + a10y * wy;
    float r1x = a01x * omy + a11x * wy;
    float r1y = a01y * omy + a11y * wy;
    dx = (r0x * wA + r1x * wB) * 256.0f;  // * (W/2), exact pow2
    dy = (r0y * wA + r1y * wB) * 256.0f;
}

__device__ __forceinline__ u32 pack16(float x, float y) {
    __half hx = __float2half_rn(x), hy = __float2half_rn(y);
    return ((u32)__half_as_ushort(hy) << 16) | (u32)__half_as_ushort(hx);
}
__device__ __forceinline__ float2 unpack16(u32 p) {
    float2 f;
    f.x = __half2float(__ushort_as_half((unsigned short)(p & 0xFFFFu)));
    f.y = __half2float(__ushort_as_half((unsigned short)(p >> 16)));
    return f;
}

__device__ __forceinline__ u64 shfl_left(u64 v) {
    unsigned lo = __shfl_up((unsigned)v, 1);
    unsigned hi = __shfl_up((unsigned)(v >> 32), 1);
    u64 r = ((u64)hi << 32) | lo;
    return (threadIdx.x & 63) ? r : 0ull;
}
__device__ __forceinline__ u64 shfl_right(u64 v) {
    unsigned lo = __shfl_down((unsigned)v, 1);
    unsigned hi = __shfl_down((unsigned)(v >> 32), 1);
    u64 r = ((u64)hi << 32) | lo;
    return ((threadIdx.x & 63) == 63) ? 0ull : r;
}

// ---------------------------------------------------------------------------
// Pass 1: evaluate every source ONCE (bit-exact decisions), store payload
// pay[b][j] = half2(-dx,-dy), append u32 entry (yi&15)<<27|xi<<18|j into
// bucket[(b, band=yi>>4)]. 1024-thread blocks (vs 256 in R9): 4x fewer
// global gcount atomics (~16K total) and ~580 B per-band write bursts
// (full-line coalescing) — this was R9's regression (pre_k ~28 us).
// bid&7 = batch -> batch b pinned to XCD b (round-robin heuristic).
// ---------------------------------------------------------------------------
__launch_bounds__(1024)
__global__ void pre_k(const float* __restrict__ src,
                      const float* __restrict__ base,
                      u32* __restrict__ pay,
                      u32* __restrict__ gcount,
                      u32* __restrict__ bucket) {
    __shared__ u32 cnt[NB];
    __shared__ u32 bbase[NB];

    int bid = blockIdx.x;
    int b   = bid & 7;
    int t   = bid >> 3;                    // 0..255
    int j   = t * 1024 + threadIdx.x;      // per-batch source index
    int y   = j >> 9;
    int x   = j & (W_ - 1);

    if (threadIdx.x < NB) cnt[threadIdx.x] = 0;
    __syncthreads();

    float dx, dy;
    bilin_disp(src, base, b, y, x, dx, dy);
    pay[b * HW_ + j] = pack16(-dx, -dy);

    int xi = (int)rintf((float)x + dx);    // round-half-even == jnp.round
    int yi = (int)rintf((float)y + dy);
    bool inb = (xi >= 0 && xi < W_ && yi >= 0 && yi < H_);
    int band = 0, rank = 0;
    if (inb) {
        band = yi >> 4;
        rank = atomicAdd(&cnt[band], 1u);
    }
    __syncthreads();
    if (threadIdx.x < NB && cnt[threadIdx.x] > 0)
        bbase[threadIdx.x] = atomicAdd(&gcount[b * NB + threadIdx.x],
                                       cnt[threadIdx.x]);
    __syncthreads();
    if (inb) {
        u32 slotn = bbase[band] + rank;
        if (slotn < CAPB) {
            u32 e = ((u32)(yi & 15) << 27) | ((u32)xi << 18) | (u32)j;
            bucket[(b * NB + band) * CAPB + slotn] = e;
        }
    }
}

// ---------------------------------------------------------------------------
// Pass 2: fused bucket-scatter + in-place key->value + 5x diffusion +
// 5x erosion + compose. 512 blocks (64 8-row tiles x 8 batches), id&7 =
// batch (XCD pin). ONE 59.5 KB LDS u32 plane (28 x 531): holds j-keys
// during scatter/mask-build, then is overwritten IN PLACE with half2
// payloads (empty -> 0) — 2 blocks/CU co-resident, 32 waves/CU (vs 16 in
// R9; that was the 62-us latency wall).
//
// Stencil correctness — same geometry as verified R7-R9 (halo 10):
// out-of-padded-array cells pinned unmasked via validm (JAX False pad;
// mask never reaches padded cols/rows 0/523 so the True-pad erosion rule
// never fires). Mask exact at ring>=5 after 5 dilations, >=10 after 5
// erosions = output region (bits 10..17, lanes 16..47). Value updates
// restricted to bits 6..21 x lanes 6..57; every cell in an output value
// cone is exact; zero-value contamination from ring-5 unwritten cells
// advances <=1 ring/iter -> capped at ring 9 < 10. In-place value safety:
// writers have old-mask 0, readers read old-mask-1 cells (disjoint);
// barrier between iterations; overlapping waves write identical values.
// Empty cells hold 0 (finite) so branchless wq=0 terms add exact 0
// (R6 NaN lesson).
// ---------------------------------------------------------------------------
__launch_bounds__(1024, 8)
__global__ void fused4_k(const u32* __restrict__ pay,
                         const u32* __restrict__ gcount,
                         const u32* __restrict__ bucket,
                         const float* __restrict__ kern,
                         const float* __restrict__ tgt,
                         float* __restrict__ out) {
    __shared__ u32 plane[WR * VSTR];       // 59472 B

    int id   = blockIdx.x;                 // 0..511
    int b    = id & 7;                     // batch == XCD (round-robin pin)
    int tile = id >> 3;                    // 0..63
    int Y0   = tile * TO_Y;
    int w0   = Y0 - 10;                    // window row 0 (output coords)
    int tid  = threadIdx.x;

    float kw[9];
#pragma unroll
    for (int q = 0; q < 9; q++) kw[q] = kern[q];

    // ---- phase 0: init keys ----
    for (int i = tid; i < WR * VSTR; i += 1024) plane[i] = INFW;
    __syncthreads();

    // ---- phase 1: scatter j-keys from 2-3 buckets (exact coverage) ----
    {
        int qlo = max(0, w0 >> 4);
        int qhi = min(NB - 1, (w0 + WR - 1) >> 4);
        for (int q = qlo; q <= qhi; q++) {
            u32 cntq = min(gcount[b * NB + q], (u32)CAPB);
            const u32* bk = bucket + (b * NB + q) * CAPB;
            int ybase = q * BND - w0;      // band row 0 in window coords
            for (u32 i = tid; i < cntq; i += 1024) {
                u32 e  = bk[i];
                int wr = ybase + (int)((e >> 27) & 15u);
                if ((unsigned)wr < WR) {
                    int xc = (int)((e >> 18) & 511u);
                    atomicMin(&plane[wr * VSTR + xc + COFF], e & 0x3FFFFu);
                }
            }
        }
    }
    __syncthreads();

    // ---- phase 2: per-lane column mask (keys still live) ----
    int wv   = tid >> 6;
    int lane = tid & 63;
    int col  = 32 * wv - 16 + lane;        // output-coord column of this lane
    int cls  = col + COFF;                 // plane column index
    bool colin = (col >= -COFF) && (col <= W_ + 5);   // padded cols [-6,517]

    u64 m = 0;
    if (colin) {
#pragma unroll 7
        for (int r = 0; r < WR; r++)
            m |= (u64)(plane[r * VSTR + cls] != INFW) << r;
    }
    __syncthreads();

    // ---- phase 3: in-place key -> payload overwrite (empty -> 0) ----
    {
        const u32* pb = pay + b * HW_;
        for (int idx = tid; idx < WR * PC; idx += 1024) {
            int rr = idx / PC;
            int cc = idx - rr * PC;
            int off = rr * VSTR + cc;
            u32 k = plane[off];
            plane[off] = (k != INFW) ? pb[k] : 0u;
        }
    }
    __syncthreads();

    int rlo = max(0, -COFF - w0);
    int rhi = min(WR - 1, (W_ + 5) - w0);
    u64 validm = colin ? ((((u64)1 << (rhi - rlo + 1)) - 1) << rlo) : 0ull;

    const u64 VROWS = (((u64)1 << 16) - 1) << 6;   // bits 6..21
    bool vlane = (lane >= 6 && lane <= 57);

    // ---- phase 4: 5 diffusion iterations ----
    for (int it = 0; it < 5; it++) {
        u64 mL = shfl_left(m), mR = shfl_right(m);
        u64 cand = ~m & ((m << 1) | (m >> 1) | mL | mR) & validm;
        u64 cv = vlane ? (cand & VROWS) : 0ull;
        while (cv) {
            int r = __builtin_ctzll(cv);
            cv &= cv - 1;
            float s = 0.0f, ax = 0.0f, ay = 0.0f;
#pragma unroll
            for (int dr = -1; dr <= 1; dr++) {
#pragma unroll
                for (int dc = -1; dc <= 1; dc++) {
                    if (dr == 0 && dc == 0) continue;
                    u64 nm = (dc < 0) ? mL : ((dc > 0) ? mR : m);
                    float wq = ((nm >> (r + dr)) & 1)
                                 ? kw[(dr + 1) * 3 + (dc + 1)] : 0.0f;
                    int cc = min(max(cls + dc, 0), PC - 1);  // clamp: wq==0 there
                    float2 nv = unpack16(plane[(r + dr) * VSTR + cc]);
                    s += wq; ax += wq * nv.x; ay += wq * nv.y;
                }
            }
            float rs = __builtin_amdgcn_rcpf(s);   // ~1e-7 rel err, way in tol
            plane[r * VSTR + cls] = pack16(ax * rs, ay * rs);
        }
        m |= cand;
        __syncthreads();
    }

    // ---- phase 5: 5 erosion iterations (registers only) + compose ----
    for (int it = 0; it < 5; it++) {
        u64 mL = shfl_left(m), mR = shfl_right(m);
        m &= (m << 1) & (m >> 1) & mL & mR;
    }

    if (lane >= 16 && lane < 48) {
#pragma unroll 4
        for (int r = 10; r < 10 + TO_Y; r++) {
            int row = w0 + r;              // Y0 .. Y0+7, always in [0,512)
            bool on = (m >> r) & 1;
            float vx, vy;
            if (on) {
                float2 t = unpack16(plane[r * VSTR + cls]);
                vx = t.x * (1.0f / 256.0f);   // 2/W exact
                vy = t.y * (1.0f / 256.0f);   // 2/H exact
            } else {
                vx = 4.0f; vy = 4.0f;
            }
            int ti = (row * W_ + col) * 2;
            float2 tg = *(const float2*)(tgt + ti);
            float2 ov; ov.x = tg.x + vx; ov.y = tg.y + vy;
            ((float2*)out)[(size_t)b * HW_ + row * W_ + col] = ov;
        }
    }
}

extern "C" void kernel_launch(void* const* d_in, const int* in_sizes, int n_in,
                              void* d_out, int out_size, void* d_ws, size_t ws_size,
                              hipStream_t stream) {
    const float* src  = (const float*)d_in[0];  // (8,256,256,2)
    const float* kern = (const float*)d_in[1];  // (3,3)
    const float* base = (const float*)d_in[2];  // (1,256,256,2)
    const float* tgt  = (const float*)d_in[3];  // (1,512,512,2)
    float* out = (float*)d_out;                 // (8,512,512,2)

    char* ws = (char*)d_ws;
    u32* gcount = (u32*)ws;                                   // 1 KB
    u32* pay    = (u32*)(ws + 1024);                          // 8 MB
    u32* bucket = (u32*)(ws + 1024 + (size_t)B_ * HW_ * 4);   // 16.8 MB

    hipMemsetAsync(gcount, 0, B_ * NB * sizeof(u32), stream);

    pre_k<<<(B_ * HW_) / 1024, 1024, 0, stream>>>(src, base, pay, gcount, bucket);
    fused4_k<<<512, 1024, 0, stream>>>(pay, gcount, bucket, kern, tgt, out);
}

// Round 11
// 136.915 us; speedup vs baseline: 1.0600x; 1.0206x over previous
//
#include <hip/hip_runtime.h>
#include <hip/hip_fp16.h>

typedef unsigned long long u64;
typedef unsigned int u32;
typedef float float4a __attribute__((ext_vector_type(4), aligned(4)));

// Problem constants (setup_inputs: B=8, Hs=Ws=256, H=W=512, niter=5)
#define B_    8
#define HS_   256
#define WS_   256
#define H_    512
#define W_    512
#define HW_   (H_ * W_)
#define TO_Y  16                 // output rows per block
#define NTILE 32                 // row tiles per batch
#define WR    36                 // window rows = TO_Y + 2*10
#define WCOLS 276                // window cols = 256 + 2*10
#define WSTR  277                // LDS plane stride (odd)
#define NBAND 32                 // 16-row bands per batch
#define NBKT  64                 // buckets per batch = band*2 + xhalf
#define INFW  0xFFFFFFFFu
#define CAPB  8192               // bucket capacity (expected ~4.2K, ~2x margin)

// ---------------------------------------------------------------------------
// Bilinear upsample of (src - base), bit-exact vs the numpy reference
// (contraction off; same op order). Pixel PAIRS load as float4 (16 B).
// x0==255 (only output col 511, wx==0): shift pair to (254,255), weights
// (0,1) — identical result.
// ---------------------------------------------------------------------------
__device__ __forceinline__ void bilin_disp(const float* __restrict__ src,
                                           const float* __restrict__ base,
                                           int b, int y, int x,
                                           float& dx, float& dy) {
#pragma clang fp contract(off)
    float cy = ((float)y + 0.5f) * 0.5f - 0.5f;
    cy = fminf(fmaxf(cy, 0.0f), 255.0f);
    int   y0 = (int)floorf(cy);
    int   y1 = min(y0 + 1, HS_ - 1);
    float wy = cy - (float)y0;

    float cx = ((float)x + 0.5f) * 0.5f - 0.5f;
    cx = fminf(fmaxf(cx, 0.0f), 255.0f);
    int   x0 = (int)floorf(cx);
    float wx = cx - (float)x0;

    float omy = 1.0f - wy;
    float wA, wB;
    int xs;
    if (x0 >= WS_ - 1) { xs = WS_ - 2; wA = 0.0f; wB = 1.0f; }
    else               { xs = x0;      wA = 1.0f - wx; wB = wx; }

    const float4a* S0 = (const float4a*)(src  + ((b * HS_ + y0) * WS_ + xs) * 2);
    const float4a* S1 = (const float4a*)(src  + ((b * HS_ + y1) * WS_ + xs) * 2);
    const float4a* B0 = (const float4a*)(base + (y0 * WS_ + xs) * 2);
    const float4a* B1 = (const float4a*)(base + (y1 * WS_ + xs) * 2);
    float4a s0 = *S0, s1 = *S1, b0 = *B0, b1 = *B1;

    float a00x = s0.x - b0.x, a00y = s0.y - b0.y;
    float a01x = s0.z - b0.z, a01y = s0.w - b0.w;
    float a10x = s1.x - b1.x, a10y = s1.y - b1.y;
    float a11x = s1.z - b1.z, a11y = s1.w - b1.w;

    float r0x = a00x * omy + a10x * wy;   // blend along y first (matches ref)
    float r0y = a00y * omy + a10y * wy;
    float r1x = a01x * omy + a11x * wy;
    float r1y = a01y * omy + a11y * wy;
    dx = (r0x * wA + r1x * wB) * 256.0f;  // * (W/2), exact pow2
    dy = (r0y * wA + r1y * wB) * 256.0f;
}

__device__ __forceinline__ u32 pack16(float x, float y) {
    __half hx = __float2half_rn(x), hy = __float2half_rn(y);
    return ((u32)__half_as_ushort(hy) << 16) | (u32)__half_as_ushort(hx);
}
__device__ __forceinline__ float2 unpack16(u32 p) {
    float2 f;
    f.x = __half2float(__ushort_as_half((unsigned short)(p & 0xFFFFu)));
    f.y = __half2float(__ushort_as_half((unsigned short)(p >> 16)));
    return f;
}

__device__ __forceinline__ u64 shfl_left(u64 v) {
    unsigned lo = __shfl_up((unsigned)v, 1);
    unsigned hi = __shfl_up((unsigned)(v >> 32), 1);
    u64 r = ((u64)hi << 32) | lo;
    return (threadIdx.x & 63) ? r : 0ull;
}
__device__ __forceinline__ u64 shfl_right(u64 v) {
    unsigned lo = __shfl_down((unsigned)v, 1);
    unsigned hi = __shfl_down((unsigned)(v >> 32), 1);
    u64 r = ((u64)hi << 32) | lo;
    return ((threadIdx.x & 63) == 63) ? 0ull : r;
}

// ---------------------------------------------------------------------------
// Pass 1: evaluate every source ONCE (bit-exact decisions), store payload
// pay[b][j] = half2(-dx,-dy), append u32 entry (yi&15)<<27|xi<<18|j into
// bucket[b][band*2 + (xi>>8)]. Entries with xi in the 20-col boundary
// sliver [246,265] are DUPLICATED into the neighboring half's bucket, so
// each consumer window reads exactly its own buckets with no xi filtering.
// bid&7 = batch -> XCD pin (round-robin heuristic).
// ---------------------------------------------------------------------------
__launch_bounds__(1024)
__global__ void pre_k(const float* __restrict__ src,
                      const float* __restrict__ base,
                      u32* __restrict__ pay,
                      u32* __restrict__ gcount,
                      u32* __restrict__ bucket) {
    __shared__ u32 cnt[NBKT];
    __shared__ u32 bbase[NBKT];

    int bid = blockIdx.x;
    int b   = bid & 7;
    int t   = bid >> 3;                    // 0..255
    int j   = t * 1024 + threadIdx.x;      // per-batch source index
    int y   = j >> 9;
    int x   = j & (W_ - 1);

    if (threadIdx.x < NBKT) cnt[threadIdx.x] = 0;
    __syncthreads();

    float dx, dy;
    bilin_disp(src, base, b, y, x, dx, dy);
    pay[b * HW_ + j] = pack16(-dx, -dy);

    int xi = (int)rintf((float)x + dx);    // round-half-even == jnp.round
    int yi = (int)rintf((float)y + dy);
    bool inb = (xi >= 0 && xi < W_ && yi >= 0 && yi < H_);
    int bk0 = 0, bk1 = -1;
    u32 r0 = 0, r1 = 0, e = 0;
    if (inb) {
        int band = yi >> 4;
        bk0 = band * 2 + (xi >> 8);
        r0 = atomicAdd(&cnt[bk0], 1u);
        if      (xi >= 246 && xi <= 255) bk1 = band * 2 + 1;  // left sliver -> right bucket
        else if (xi >= 256 && xi <= 265) bk1 = band * 2;      // right sliver -> left bucket
        if (bk1 >= 0) r1 = atomicAdd(&cnt[bk1], 1u);
        e = ((u32)(yi & 15) << 27) | ((u32)xi << 18) | (u32)j;
    }
    __syncthreads();
    if (threadIdx.x < NBKT) {
        u32 c = cnt[threadIdx.x];
        bbase[threadIdx.x] = c ? atomicAdd(&gcount[b * NBKT + threadIdx.x], c)
                               : 0u;
    }
    __syncthreads();
    if (inb) {
        u32 s0 = bbase[bk0] + r0;
        if (s0 < CAPB) bucket[(b * NBKT + bk0) * CAPB + s0] = e;
        if (bk1 >= 0) {
            u32 s1 = bbase[bk1] + r1;
            if (s1 < CAPB) bucket[(b * NBKT + bk1) * CAPB + s1] = e;
        }
    }
}

// ---------------------------------------------------------------------------
// Pass 2: fused bucket-scatter + in-place key->value + 5x diffusion +
// 5x erosion + compose. 512 blocks = 32 row-tiles x 2 x-halves x 8 batches
// (id&7 = batch -> XCD pin); 512 threads = 8 waves = the 8 column slices.
// Window 36 x 276 (u32 plane, stride 277, 39.9 KB) -> 2 blocks/CU.
// vs R10: same occupancy but window cells 5.09M total (vs 7.6M) — the
// VALU-bound per-cell work (R10 post-mortem) shrinks ~1.5x.
//
// Per-wave stencil geometry identical to verified R7-R10 (lane = column,
// 32-col output slice + 16-lane halos; u64 bitmask over WR=36 rows):
// out-of-window / out-of-padded-array lanes pinned m=0, validm=0 — they are
// wrong-from-start cells >=10 lanes/bits from any output cell, so the
// standard halo-10 staleness bound covers them (1 ring/iter, 10 iters).
// Mask exact at ring>=5 after dilations, >=10 after erosions = output
// (bits 10..25, lanes 16..47). Value updates restricted to bits 6..29 x
// lanes 6..57 (always-exact interior); zero-value contamination capped at
// ring 9 < 10. In-place safety: value writers have old-mask 0, readers
// read old-mask-1 cells (disjoint); barrier between iterations. Empty
// cells hold 0 (finite) so branchless wq=0 terms add exact 0 (R6 lesson).
// ---------------------------------------------------------------------------
__launch_bounds__(512, 2)
__global__ void fused5_k(const u32* __restrict__ pay,
                         const u32* __restrict__ gcount,
                         const u32* __restrict__ bucket,
                         const float* __restrict__ kern,
                         const float* __restrict__ tgt,
                         float* __restrict__ out) {
    __shared__ u32 plane[WR * WSTR];       // 39888 B

    int id   = blockIdx.x;                 // 0..511
    int b    = id & 7;                     // batch == XCD (round-robin pin)
    int rest = id >> 3;                    // 0..63
    int tile = rest >> 1;                  // 0..31
    int half = rest & 1;
    int X0   = half << 8;
    int Y0   = tile * TO_Y;
    int w0   = Y0 - 10;                    // window row 0 (output coords)
    int wc0  = X0 - 10;                    // window col 0 (output coords)
    int tid  = threadIdx.x;

    float kw[9];
#pragma unroll
    for (int q = 0; q < 9; q++) kw[q] = kern[q];

    // ---- phase 0: init keys ----
    for (int i = tid; i < WR * WSTR; i += 512) plane[i] = INFW;
    __syncthreads();

    // ---- phase 1: scatter j-keys from this half's 2-3 band buckets ----
    {
        int qlo = max(0, w0 >> 4);
        int qhi = min(NBAND - 1, (w0 + WR - 1) >> 4);
        for (int q = qlo; q <= qhi; q++) {
            int bki = b * NBKT + q * 2 + half;
            u32 cntq = min(gcount[bki], (u32)CAPB);
            const u32* bk = bucket + bki * CAPB;
            int ybase = q * 16 - w0;       // band row 0 in window coords
            for (u32 i = tid; i < cntq; i += 512) {
                u32 e  = bk[i];
                int wr = ybase + (int)((e >> 27) & 15u);
                if ((unsigned)wr < WR) {
                    int xc = (int)((e >> 18) & 511u) - wc0;  // always in [0,275]
                    atomicMin(&plane[wr * WSTR + xc], e & 0x3FFFFu);
                }
            }
        }
    }
    __syncthreads();

    // ---- phase 2: per-lane column mask (keys still live) ----
    int wv   = tid >> 6;
    int lane = tid & 63;
    int col  = X0 + 32 * wv - 16 + lane;   // output-coord column of this lane
    int cls  = col - wc0;                  // plane column index
    bool inwin = ((unsigned)cls < WCOLS);
    bool colin = inwin && (col >= -6) && (col <= W_ + 5);  // padded [-6,517]

    u64 m = 0;
    if (colin) {
#pragma unroll 6
        for (int r = 0; r < WR; r++)
            m |= (u64)(plane[r * WSTR + cls] != INFW) << r;
    }
    __syncthreads();

    // ---- phase 3: in-place key -> payload overwrite (empty -> 0) ----
    {
        const u32* pb = pay + b * HW_;
        for (int idx = tid; idx < WR * WCOLS; idx += 512) {
            int rr = idx / WCOLS;
            int cc = idx - rr * WCOLS;
            int off = rr * WSTR + cc;
            u32 k = plane[off];
            plane[off] = (k != INFW) ? pb[k] : 0u;
        }
    }
    __syncthreads();

    int rlo = max(0, -6 - w0);
    int rhi = min(WR - 1, (W_ + 5) - w0);
    u64 validm = colin ? ((((u64)1 << (rhi - rlo + 1)) - 1) << rlo) : 0ull;

    const u64 VROWS = (((u64)1 << 24) - 1) << 6;   // bits 6..29
    bool vlane = (lane >= 6 && lane <= 57);

    // ---- phase 4: 5 diffusion iterations ----
    for (int it = 0; it < 5; it++) {
        u64 mL = shfl_left(m), mR = shfl_right(m);
        u64 cand = ~m & ((m << 1) | (m >> 1) | mL | mR) & validm;
        u64 cv = vlane ? (cand & VROWS) : 0ull;
        while (cv) {
            int r = __builtin_ctzll(cv);
            cv &= cv - 1;
            float s = 0.0f, ax = 0.0f, ay = 0.0f;
#pragma unroll
            for (int dr = -1; dr <= 1; dr++) {
#pragma unroll
                for (int dc = -1; dc <= 1; dc++) {
                    if (dr == 0 && dc == 0) continue;
                    u64 nm = (dc < 0) ? mL : ((dc > 0) ? mR : m);
                    float wq = ((nm >> (r + dr)) & 1)
                                 ? kw[(dr + 1) * 3 + (dc + 1)] : 0.0f;
                    int cc = min(max(cls + dc, 0), WCOLS - 1); // clamp: wq==0 there
                    float2 nv = unpack16(plane[(r + dr) * WSTR + cc]);
                    s += wq; ax += wq * nv.x; ay += wq * nv.y;
                }
            }
            float rs = __builtin_amdgcn_rcpf(s);   // ~1e-7 rel err, in tol
            plane[r * WSTR + cls] = pack16(ax * rs, ay * rs);
        }
        m |= cand;
        __syncthreads();
    }

    // ---- phase 5: 5 erosion iterations (registers only) + compose ----
    for (int it = 0; it < 5; it++) {
        u64 mL = shfl_left(m), mR = shfl_right(m);
        m &= (m << 1) & (m >> 1) & mL & mR;
    }

    if (lane >= 16 && lane < 48) {
#pragma unroll 4
        for (int r = 10; r < 10 + TO_Y; r++) {
            int row = w0 + r;              // Y0 .. Y0+15, always in [0,512)
            bool on = (m >> r) & 1;
            float vx, vy;
            if (on) {
                float2 t = unpack16(plane[r * WSTR + cls]);
                vx = t.x * (1.0f / 256.0f);   // 2/W exact
                vy = t.y * (1.0f / 256.0f);   // 2/H exact
            } else {
                vx = 4.0f; vy = 4.0f;
            }
            int ti = (row * W_ + col) * 2;
            float2 tg = *(const float2*)(tgt + ti);
            float2 ov; ov.x = tg.x + vx; ov.y = tg.y + vy;
            ((float2*)out)[(size_t)b * HW_ + row * W_ + col] = ov;
        }
    }
}

extern "C" void kernel_launch(void* const* d_in, const int* in_sizes, int n_in,
                              void* d_out, int out_size, void* d_ws, size_t ws_size,
                              hipStream_t stream) {
    const float* src  = (const float*)d_in[0];  // (8,256,256,2)
    const float* kern = (const float*)d_in[1];  // (3,3)
    const float* base = (const float*)d_in[2];  // (1,256,256,2)
    const float* tgt  = (const float*)d_in[3];  // (1,512,512,2)
    float* out = (float*)d_out;                 // (8,512,512,2)

    char* ws = (char*)d_ws;
    u32* gcount = (u32*)ws;                                   // 2 KB (pad 4K)
    u32* pay    = (u32*)(ws + 4096);                          // 8 MB
    u32* bucket = (u32*)(ws + 4096 + (size_t)B_ * HW_ * 4);   // 16.8 MB

    hipMemsetAsync(gcount, 0, B_ * NBKT * sizeof(u32), stream);

    pre_k<<<(B_ * HW_) / 1024, 1024, 0, stream>>>(src, base, pay, gcount, bucket);
    fused5_k<<<512, 512, 0, stream>>>(pay, gcount, bucket, kern, tgt, out);
}